// Round 1
// baseline (249.814 us; speedup 1.0000x reference)
//
#include <hip/hip_runtime.h>
#include <hip/hip_bf16.h>
#include <math.h>

#define D 40
#define DIN 128
#define S 2048
#define B 8
#define NROWS (B*S)   // 16384

// ---------------- Kernel 1: adapter + rmsnorm + QKV projection ----------------
// 16 rows per block, 256 threads (4 waves), one row per wave per iteration.
__global__ __launch_bounds__(256) void k1_adapter_qkv(
    const float* __restrict__ embs, const float* __restrict__ Wa,
    const float* __restrict__ ba, const float* __restrict__ ln1,
    const float* __restrict__ Wq, const float* __restrict__ Wk, const float* __restrict__ Wv,
    float* __restrict__ x, float* __restrict__ q, float* __restrict__ k, float* __restrict__ v)
{
    __shared__ float sWa[DIN*D];
    __shared__ float sWq[D*D], sWk[D*D], sWv[D*D];
    __shared__ float sba[D], sln[D];
    __shared__ float sE[4][DIN];
    __shared__ float sH[4][D];

    int tid = threadIdx.x;
    for (int i = tid; i < DIN*D; i += 256) sWa[i] = Wa[i];
    for (int i = tid; i < D*D; i += 256) { sWq[i]=Wq[i]; sWk[i]=Wk[i]; sWv[i]=Wv[i]; }
    if (tid < D) { sba[tid]=ba[tid]; sln[tid]=ln1[tid]; }
    __syncthreads();

    int wave = tid >> 6, lane = tid & 63;
    int base = blockIdx.x * 16;

    for (int it = 0; it < 4; ++it) {
        int row = base + it*4 + wave;
        // load embs row (128 floats) into this wave's LDS slice
        sE[wave][lane]      = embs[row*DIN + lane];
        sE[wave][lane + 64] = embs[row*DIN + lane + 64];
        __syncthreads();

        float xj = 0.f;
        if (lane < D) {
            float acc = sba[lane];
            #pragma unroll 8
            for (int i = 0; i < DIN; ++i) acc += sE[wave][i] * sWa[i*D + lane];
            xj = fmaxf(acc, 0.f);
            x[row*D + lane] = xj;
        }
        // wave-wide sum of squares (lanes >= D contribute 0)
        float ss = xj * xj;
        #pragma unroll
        for (int off = 32; off; off >>= 1) ss += __shfl_down(ss, off);
        ss = __shfl(ss, 0);
        float inv = rsqrtf(ss * (1.0f/D) + 1e-6f);
        if (lane < D) sH[wave][lane] = xj * inv * sln[lane];
        __syncthreads();

        if (lane < D) {
            float aq = 0.f, ak = 0.f, av = 0.f;
            #pragma unroll
            for (int i = 0; i < D; ++i) {
                float h = sH[wave][i];
                aq += h * sWq[i*D + lane];
                ak += h * sWk[i*D + lane];
                av += h * sWv[i*D + lane];
            }
            q[row*D + lane] = aq;
            k[row*D + lane] = ak;
            v[row*D + lane] = av;
        }
        __syncthreads();
    }
}

// ---------------- Kernel 2: relative-position bias table ----------------
// btab[t] = rel_bias[bucket(rel)] for rel = t - 2047, t in [0, 4095)
__global__ void k2_bias_table(const float* __restrict__ rel_bias, float* __restrict__ btab)
{
    int t = blockIdx.x * 256 + threadIdx.x;
    if (t >= 2*S - 1) return;
    int rel = t - (S - 1);          // rel = k - q
    int bucket = (rel > 0) ? 16 : 0;
    int ar = rel < 0 ? -rel : rel;
    int add;
    if (ar < 8) {
        add = ar;
    } else {
        float tt = logf((float)ar * 0.125f) / logf(16.0f) * 8.0f;
        int lg = 8 + (int)tt;
        add = lg < 15 ? lg : 15;
    }
    btab[t] = rel_bias[bucket + add];
}

// ---------------- Kernel 3: fused flash attention ----------------
// grid (S/QB, B), 256 threads. QB=32 q-rows per block (8 per wave).
// Within a wave: lane = qr*8 + kg ; qr in [0,8) selects q-row, kg in [0,8)
// splits the 64-row K/V tile. Scores are tiny (|s| < ~1) -> no max-subtraction.
#define QB 32
#define KB 64
#define KSTR 44   // padded LDS row stride (floats): conflict-free for kg-pattern
__global__ __launch_bounds__(256) void k3_attention(
    const float* __restrict__ q, const float* __restrict__ kmat,
    const float* __restrict__ vmat, const float* __restrict__ btab,
    float* __restrict__ aout)
{
    __shared__ float sK[KB*KSTR];
    __shared__ float sV[KB*KSTR];

    int b  = blockIdx.y;
    int q0 = blockIdx.x * QB;
    int tid = threadIdx.x, wave = tid >> 6, lane = tid & 63;
    int qr = lane >> 3;          // 0..7
    int kg = lane & 7;           // 0..7
    int qrow = q0 + wave*8 + qr; // 0..2047

    const float* qptr = q + (size_t)(b*S + qrow)*D;
    float qreg[D];
    #pragma unroll
    for (int d = 0; d < D; ++d) qreg[d] = qptr[d];

    float l = 0.f;
    float o[D];
    #pragma unroll
    for (int d = 0; d < D; ++d) o[d] = 0.f;

    const float* kb = kmat + (size_t)b*S*D;
    const float* vb = vmat + (size_t)b*S*D;
    const float* bt = btab + (S - 1) - qrow;   // bt[kidx] = btab[kidx - qrow + 2047]

    for (int kt = 0; kt < S; kt += KB) {
        __syncthreads();
        // stage K/V tile (64 rows x 40 floats, contiguous in global) as float4
        const float4* kg4 = (const float4*)(kb + (size_t)kt*D);
        const float4* vg4 = (const float4*)(vb + (size_t)kt*D);
        for (int i = tid; i < KB*D/4; i += 256) {
            int e = i*4; int r = e/D; int c = e - r*D;
            *(float4*)&sK[r*KSTR + c] = kg4[i];
            *(float4*)&sV[r*KSTR + c] = vg4[i];
        }
        __syncthreads();

        #pragma unroll
        for (int jk = 0; jk < KB/8; ++jk) {
            int kk = jk*8 + kg;
            const float* kr = &sK[kk*KSTR];
            float s = bt[kt + kk];
            #pragma unroll
            for (int d = 0; d < D; ++d) s += qreg[d] * kr[d];
            float e = __expf(s);
            l += e;
            const float* vr = &sV[kk*KSTR];
            #pragma unroll
            for (int d = 0; d < D; ++d) o[d] += e * vr[d];
        }
    }

    // reduce over the 8 kg lanes sharing this q-row
    #pragma unroll
    for (int m = 1; m < 8; m <<= 1) l += __shfl_xor(l, m);
    float inv = 1.f / l;
    #pragma unroll
    for (int d = 0; d < D; ++d) {
        float val = o[d];
        #pragma unroll
        for (int m = 1; m < 8; m <<= 1) val += __shfl_xor(val, m);
        o[d] = val * inv;
    }
    float* op = aout + (size_t)(b*S + qrow)*D;
    for (int d = kg; d < D; d += 8) op[d] = o[d];
}

// ---------------- Kernel 4: O-proj + residual + FF + final rmsnorm ----------------
__global__ __launch_bounds__(256) void k4_out_ff(
    const float* __restrict__ x, const float* __restrict__ attn,
    const float* __restrict__ Wo, const float* __restrict__ ln2,
    const float* __restrict__ wi, const float* __restrict__ wo,
    const float* __restrict__ lnf, float* __restrict__ out)
{
    __shared__ float sWo[D*D], sWi[D*D], sWo2[D*D];
    __shared__ float sln2[D], slnf[D];
    __shared__ float sA[4][D], sB2[4][D];

    int tid = threadIdx.x;
    for (int i = tid; i < D*D; i += 256) { sWo[i]=Wo[i]; sWi[i]=wi[i]; sWo2[i]=wo[i]; }
    if (tid < D) { sln2[tid]=ln2[tid]; slnf[tid]=lnf[tid]; }
    __syncthreads();

    int wave = tid >> 6, lane = tid & 63;
    int base = blockIdx.x * 16;

    for (int it = 0; it < 4; ++it) {
        int row = base + it*4 + wave;
        if (lane < D) sA[wave][lane] = attn[row*D + lane];
        __syncthreads();

        float x2 = 0.f;
        if (lane < D) {
            float acc = 0.f;
            #pragma unroll
            for (int i = 0; i < D; ++i) acc += sA[wave][i] * sWo[i*D + lane];
            x2 = x[row*D + lane] + acc;
        }
        float ss = x2 * x2;
        #pragma unroll
        for (int off = 32; off; off >>= 1) ss += __shfl_down(ss, off);
        ss = __shfl(ss, 0);
        float inv = rsqrtf(ss * (1.0f/D) + 1e-6f);
        if (lane < D) sB2[wave][lane] = x2 * inv * sln2[lane];
        __syncthreads();

        float f1 = 0.f;
        if (lane < D) {
            float acc = 0.f;
            #pragma unroll
            for (int i = 0; i < D; ++i) acc += sB2[wave][i] * sWi[i*D + lane];
            f1 = fmaxf(acc, 0.f);
        }
        __syncthreads();
        if (lane < D) sA[wave][lane] = f1;
        __syncthreads();

        float x3 = 0.f;
        if (lane < D) {
            float acc = 0.f;
            #pragma unroll
            for (int i = 0; i < D; ++i) acc += sA[wave][i] * sWo2[i*D + lane];
            x3 = x2 + acc;
        }
        float ss2 = x3 * x3;
        #pragma unroll
        for (int off = 32; off; off >>= 1) ss2 += __shfl_down(ss2, off);
        ss2 = __shfl(ss2, 0);
        float inv2 = rsqrtf(ss2 * (1.0f/D) + 1e-6f);
        if (lane < D) out[row*D + lane] = x3 * inv2 * slnf[lane];
        __syncthreads();
    }
}

extern "C" void kernel_launch(void* const* d_in, const int* in_sizes, int n_in,
                              void* d_out, int out_size, void* d_ws, size_t ws_size,
                              hipStream_t stream) {
    const float* embs = (const float*)d_in[0];
    const float* Wa   = (const float*)d_in[1];
    const float* ba   = (const float*)d_in[2];
    const float* ln1  = (const float*)d_in[3];
    const float* Wq   = (const float*)d_in[4];
    const float* Wk   = (const float*)d_in[5];
    const float* Wv   = (const float*)d_in[6];
    const float* Wo   = (const float*)d_in[7];
    const float* ln2  = (const float*)d_in[8];
    const float* wi   = (const float*)d_in[9];
    const float* wo   = (const float*)d_in[10];
    const float* lnf  = (const float*)d_in[11];
    const float* rb   = (const float*)d_in[12];

    float* ws   = (float*)d_ws;
    const size_t RC = (size_t)NROWS * D;   // 655360
    float* x    = ws;
    float* q    = ws + RC;
    float* k    = ws + 2*RC;
    float* v    = ws + 3*RC;
    float* attn = ws + 4*RC;
    float* btab = ws + 5*RC;

    k1_adapter_qkv<<<NROWS/16, 256, 0, stream>>>(embs, Wa, ba, ln1, Wq, Wk, Wv, x, q, k, v);
    k2_bias_table<<<16, 256, 0, stream>>>(rb, btab);
    k3_attention<<<dim3(S/QB, B), 256, 0, stream>>>(q, k, v, btab, attn);
    k4_out_ff<<<NROWS/16, 256, 0, stream>>>(x, attn, Wo, ln2, wi, wo, lnf, (float*)d_out);
}

// Round 2
// 118.101 us; speedup vs baseline: 2.1153x; 2.1153x over previous
//
#include <hip/hip_runtime.h>
#include <hip/hip_bf16.h>
#include <math.h>

#define D 40
#define DIN 128
#define S 2048
#define B 8
#define NROWS (B*S)   // 16384
#define DP 64         // padded depth for Q/K bf16
#define DV 48         // padded depth for V bf16
#define PSTR 56       // P LDS row stride in ushorts (112B, 16B-aligned, ~2-way banks)

typedef __bf16 bf16x8 __attribute__((ext_vector_type(8)));
typedef float f32x4 __attribute__((ext_vector_type(4)));

static __device__ __forceinline__ unsigned short f2bf(float f) {
    unsigned u = __builtin_bit_cast(unsigned, f);
    u += 0x7fff + ((u >> 16) & 1);   // RNE
    return (unsigned short)(u >> 16);
}
static __device__ __forceinline__ bf16x8 ldfrag(const unsigned short* p) {
    return __builtin_bit_cast(bf16x8, *(const uint4*)p);
}

// ---------------- Kernel 1: adapter + rmsnorm + QKV (bf16 outputs) ----------------
__global__ __launch_bounds__(256) void k1_adapter_qkv(
    const float* __restrict__ embs, const float* __restrict__ Wa,
    const float* __restrict__ ba, const float* __restrict__ ln1,
    const float* __restrict__ Wq, const float* __restrict__ Wk, const float* __restrict__ Wv,
    float* __restrict__ x, unsigned short* __restrict__ qb,
    unsigned short* __restrict__ kbq, unsigned short* __restrict__ vT)
{
    __shared__ float sWa[DIN*D];
    __shared__ float sWq[D*D], sWk[D*D], sWv[D*D];
    __shared__ float sba[D], sln[D];
    __shared__ float sE[4][DIN];
    __shared__ float sH[4][D];

    int tid = threadIdx.x;
    for (int i = tid; i < DIN*D; i += 256) sWa[i] = Wa[i];
    for (int i = tid; i < D*D; i += 256) { sWq[i]=Wq[i]; sWk[i]=Wk[i]; sWv[i]=Wv[i]; }
    if (tid < D) { sba[tid]=ba[tid]; sln[tid]=ln1[tid]; }
    __syncthreads();

    int wave = tid >> 6, lane = tid & 63;
    int base = blockIdx.x * 16;

    for (int it = 0; it < 4; ++it) {
        int row = base + it*4 + wave;
        sE[wave][lane]      = embs[row*DIN + lane];
        sE[wave][lane + 64] = embs[row*DIN + lane + 64];
        __syncthreads();

        float xj = 0.f;
        if (lane < D) {
            float acc = sba[lane];
            #pragma unroll 8
            for (int i = 0; i < DIN; ++i) acc += sE[wave][i] * sWa[i*D + lane];
            xj = fmaxf(acc, 0.f);
            x[row*D + lane] = xj;
        }
        float ss = xj * xj;
        #pragma unroll
        for (int off = 32; off; off >>= 1) ss += __shfl_down(ss, off);
        ss = __shfl(ss, 0);
        float inv = rsqrtf(ss * (1.0f/D) + 1e-6f);
        if (lane < D) sH[wave][lane] = xj * inv * sln[lane];
        __syncthreads();

        float aq = 0.f, ak = 0.f, av = 0.f;
        if (lane < D) {
            #pragma unroll
            for (int i = 0; i < D; ++i) {
                float h = sH[wave][i];
                aq += h * sWq[i*D + lane];
                ak += h * sWk[i*D + lane];
                av += h * sWv[i*D + lane];
            }
        }
        qb [row*DP + lane] = (lane < D) ? f2bf(aq) : (unsigned short)0;
        kbq[row*DP + lane] = (lane < D) ? f2bf(ak) : (unsigned short)0;
        if (lane < D) vT[(size_t)lane*NROWS + row] = f2bf(av);
        __syncthreads();
    }
}

// ---------------- Kernel 2: relative-position bias table ----------------
__global__ void k2_bias_table(const float* __restrict__ rel_bias, float* __restrict__ btab)
{
    int t = blockIdx.x * 256 + threadIdx.x;
    if (t >= 2*S - 1) return;
    int rel = t - (S - 1);          // rel = k - q
    int bucket = (rel > 0) ? 16 : 0;
    int ar = rel < 0 ? -rel : rel;
    int add;
    if (ar < 8) {
        add = ar;
    } else {
        float tt = logf((float)ar * 0.125f) / logf(16.0f) * 8.0f;
        int lg = 8 + (int)tt;
        add = lg < 15 ? lg : 15;
    }
    btab[t] = rel_bias[bucket + add];
}

// ---------------- Kernel 3: fused flash attention, MFMA bf16 ----------------
// grid (S/64, B), 256 threads = 4 waves; each wave owns 16 q-rows.
// Per 32-k iter: 4 MFMA QK^T (d padded to 64) + bias/exp + P->LDS->A-frag + 3 MFMA PV.
__global__ __launch_bounds__(256) void k3_attn_mfma(
    const unsigned short* __restrict__ qb, const unsigned short* __restrict__ kb,
    const unsigned short* __restrict__ vT, const float* __restrict__ btab,
    float* __restrict__ aout)
{
    __shared__ float sbt[2*S-1];
    __shared__ unsigned short sP[4][16*PSTR];

    int tid = threadIdx.x;
    for (int i = tid; i < 2*S-1; i += 256) sbt[i] = btab[i];
    __syncthreads();

    const int w  = tid >> 6, l = tid & 63;
    const int lr = l & 15,  lg = l >> 4;
    const int b  = blockIdx.y;
    const int q0 = blockIdx.x * 64 + w * 16;

    // Q A-fragments: row = q0+lr, k-elements = lg*8..+7 (order-consistent with B loads)
    const unsigned short* qrow = qb + ((size_t)(b*S) + q0 + lr) * DP + lg*8;
    const bf16x8 qf0 = ldfrag(qrow);
    const bf16x8 qf1 = ldfrag(qrow + 32);

    f32x4 of0 = {0,0,0,0}, of1 = {0,0,0,0}, of2 = {0,0,0,0};
    float el[4] = {0.f, 0.f, 0.f, 0.f};

    const unsigned short* kbase = kb + (size_t)(b*S)*DP + (size_t)lr*DP + lg*8;
    const unsigned short* vbase = vT + (size_t)lr*NROWS + (size_t)b*S + lg*8;
    unsigned short* pw = &sP[w][0];
    const int bias0 = (S-1) - q0 - lg*4;

    bf16x8 kfA[4], vfA[3], kfB[4], vfB[3];

    auto loadK = [&](int kt, bf16x8* kf) {
        const unsigned short* p = kbase + (size_t)kt*DP;
        kf[0] = ldfrag(p);         kf[1] = ldfrag(p + 32);
        kf[2] = ldfrag(p + 16*DP); kf[3] = ldfrag(p + 16*DP + 32);
    };
    auto loadV = [&](int kt, bf16x8* vf) {
        const unsigned short* p = vbase + kt;
        vf[0] = ldfrag(p);
        vf[1] = ldfrag(p + (size_t)16*NROWS);
        vf[2] = ldfrag(p + (size_t)32*NROWS);
    };

    auto compute = [&](int kt, const bf16x8* kf, const bf16x8* vf) {
        f32x4 z = {0,0,0,0};
        f32x4 sc0 = __builtin_amdgcn_mfma_f32_16x16x32_bf16(qf0, kf[0], z, 0,0,0);
        sc0 = __builtin_amdgcn_mfma_f32_16x16x32_bf16(qf1, kf[1], sc0, 0,0,0);
        f32x4 sc1 = __builtin_amdgcn_mfma_f32_16x16x32_bf16(qf0, kf[2], z, 0,0,0);
        sc1 = __builtin_amdgcn_mfma_f32_16x16x32_bf16(qf1, kf[3], sc1, 0,0,0);

        // make sure last iter's P-frag read retired before overwriting sP
        asm volatile("s_waitcnt lgkmcnt(0)" ::: "memory");
        __builtin_amdgcn_sched_barrier(0);

        const int ib = kt + bias0 + lr;
        #pragma unroll
        for (int r = 0; r < 4; ++r) {
            float e0 = __expf(sc0[r] + sbt[ib - r]);
            float e1 = __expf(sc1[r] + sbt[ib + 16 - r]);
            el[r] += e0 + e1;
            pw[(lg*4+r)*PSTR + lr]      = f2bf(e0);   // P[q_local][k_local], C-layout coords
            pw[(lg*4+r)*PSTR + 16 + lr] = f2bf(e1);
        }
        asm volatile("s_waitcnt lgkmcnt(0)" ::: "memory");
        __builtin_amdgcn_sched_barrier(0);
        bf16x8 pf = *(const bf16x8*)(pw + lr*PSTR + lg*8);  // A-layout read back

        of0 = __builtin_amdgcn_mfma_f32_16x16x32_bf16(pf, vf[0], of0, 0,0,0);
        of1 = __builtin_amdgcn_mfma_f32_16x16x32_bf16(pf, vf[1], of1, 0,0,0);
        of2 = __builtin_amdgcn_mfma_f32_16x16x32_bf16(pf, vf[2], of2, 0,0,0);
    };

    loadK(0, kfA); loadV(0, vfA);
    for (int kt = 0; kt < S; kt += 64) {
        loadK(kt+32, kfB); loadV(kt+32, vfB);
        compute(kt, kfA, vfA);
        if (kt + 64 < S) { loadK(kt+64, kfA); loadV(kt+64, vfA); }
        compute(kt+32, kfB, vfB);
    }

    #pragma unroll
    for (int r = 0; r < 4; ++r) {
        float v = el[r];
        v += __shfl_xor(v, 1); v += __shfl_xor(v, 2);
        v += __shfl_xor(v, 4); v += __shfl_xor(v, 8);
        el[r] = 1.0f / v;
    }
    #pragma unroll
    for (int r = 0; r < 4; ++r) {
        float* pr = aout + ((size_t)(b*S) + q0 + lg*4 + r) * D;
        pr[lr]      = of0[r] * el[r];
        pr[16 + lr] = of1[r] * el[r];
        if (lr < 8) pr[32 + lr] = of2[r] * el[r];
    }
}

// ---------------- Kernel 4: O-proj + residual + FF + final rmsnorm ----------------
__global__ __launch_bounds__(256) void k4_out_ff(
    const float* __restrict__ x, const float* __restrict__ attn,
    const float* __restrict__ Wo, const float* __restrict__ ln2,
    const float* __restrict__ wi, const float* __restrict__ wo,
    const float* __restrict__ lnf, float* __restrict__ out)
{
    __shared__ float sWo[D*D], sWi[D*D], sWo2[D*D];
    __shared__ float sln2[D], slnf[D];
    __shared__ float sA[4][D], sB2[4][D];

    int tid = threadIdx.x;
    for (int i = tid; i < D*D; i += 256) { sWo[i]=Wo[i]; sWi[i]=wi[i]; sWo2[i]=wo[i]; }
    if (tid < D) { sln2[tid]=ln2[tid]; slnf[tid]=lnf[tid]; }
    __syncthreads();

    int wave = tid >> 6, lane = tid & 63;
    int base = blockIdx.x * 16;

    for (int it = 0; it < 4; ++it) {
        int row = base + it*4 + wave;
        if (lane < D) sA[wave][lane] = attn[row*D + lane];
        __syncthreads();

        float x2 = 0.f;
        if (lane < D) {
            float acc = 0.f;
            #pragma unroll
            for (int i = 0; i < D; ++i) acc += sA[wave][i] * sWo[i*D + lane];
            x2 = x[row*D + lane] + acc;
        }
        float ss = x2 * x2;
        #pragma unroll
        for (int off = 32; off; off >>= 1) ss += __shfl_down(ss, off);
        ss = __shfl(ss, 0);
        float inv = rsqrtf(ss * (1.0f/D) + 1e-6f);
        if (lane < D) sB2[wave][lane] = x2 * inv * sln2[lane];
        __syncthreads();

        float f1 = 0.f;
        if (lane < D) {
            float acc = 0.f;
            #pragma unroll
            for (int i = 0; i < D; ++i) acc += sB2[wave][i] * sWi[i*D + lane];
            f1 = fmaxf(acc, 0.f);
        }
        __syncthreads();
        if (lane < D) sA[wave][lane] = f1;
        __syncthreads();

        float x3 = 0.f;
        if (lane < D) {
            float acc = 0.f;
            #pragma unroll
            for (int i = 0; i < D; ++i) acc += sA[wave][i] * sWo2[i*D + lane];
            x3 = x2 + acc;
        }
        float ss2 = x3 * x3;
        #pragma unroll
        for (int off = 32; off; off >>= 1) ss2 += __shfl_down(ss2, off);
        ss2 = __shfl(ss2, 0);
        float inv2 = rsqrtf(ss2 * (1.0f/D) + 1e-6f);
        if (lane < D) out[row*D + lane] = x3 * inv2 * slnf[lane];
        __syncthreads();
    }
}

extern "C" void kernel_launch(void* const* d_in, const int* in_sizes, int n_in,
                              void* d_out, int out_size, void* d_ws, size_t ws_size,
                              hipStream_t stream) {
    const float* embs = (const float*)d_in[0];
    const float* Wa   = (const float*)d_in[1];
    const float* ba   = (const float*)d_in[2];
    const float* ln1  = (const float*)d_in[3];
    const float* Wq   = (const float*)d_in[4];
    const float* Wk   = (const float*)d_in[5];
    const float* Wv   = (const float*)d_in[6];
    const float* Wo   = (const float*)d_in[7];
    const float* ln2  = (const float*)d_in[8];
    const float* wi   = (const float*)d_in[9];
    const float* wo   = (const float*)d_in[10];
    const float* lnf  = (const float*)d_in[11];
    const float* rb   = (const float*)d_in[12];

    char* wsb = (char*)d_ws;
    float*          x    = (float*)(wsb);                       // NROWS*40*4 = 2,621,440
    unsigned short* qb   = (unsigned short*)(wsb + 2621440);    // NROWS*64*2 = 2,097,152
    unsigned short* kbq  = (unsigned short*)(wsb + 4718592);    // NROWS*64*2 = 2,097,152
    unsigned short* vT   = (unsigned short*)(wsb + 6815744);    // 48*NROWS*2 = 1,572,864
    float*          attn = (float*)(wsb + 8388608);             // NROWS*40*4 = 2,621,440
    float*          btab = (float*)(wsb + 11010048);            // 4095*4

    // zero-pad V rows d=40..47 (read by the PV fragment d-tile 2)
    (void)hipMemsetAsync(vT + (size_t)D*NROWS, 0, (size_t)(DV - D)*NROWS*2, stream);

    k1_adapter_qkv<<<NROWS/16, 256, 0, stream>>>(embs, Wa, ba, ln1, Wq, Wk, Wv, x, qb, kbq, vT);
    k2_bias_table<<<16, 256, 0, stream>>>(rb, btab);
    k3_attn_mfma<<<dim3(S/64, B), 256, 0, stream>>>(qb, kbq, vT, btab, attn);
    k4_out_ff<<<NROWS/16, 256, 0, stream>>>(x, attn, Wo, ln2, wi, wo, lnf, (float*)d_out);
}